// Round 6
// baseline (2069.253 us; speedup 1.0000x reference)
//
#include <hip/hip_runtime.h>

typedef __attribute__((ext_vector_type(8))) short bf16x8;
typedef __attribute__((ext_vector_type(4))) float f32x4;

// Problem constants
#define B_   16
#define C_   64
#define H_   64
#define W_   64
#define HD_  128
#define K_   320      // C + 2*HD
#define SW_  127      // H+W-1

// Decomposition: 4 hd-groups (32 hd each) x 64 col-clusters (16 cols each) = 256 blocks
#define NG    4
#define GH    32      // hd per group
#define NCG   64      // clusters
#define TC    16      // cols per cluster
#define NT    640     // threads per block (10 waves)
#define ROWS  160     // gate rows per block (5 gates x 32 hd)
#define NKT   10      // K/32 k-tiles
#define NRT   10      // ROWS/16 row-tiles (== waves)
#define SSTR  19      // Ss row stride: ODD -> conflict-free column scatters (R5 had 18: 4-way)
#define GPS   17      // gate-panel stride (odd, epilogue column reads conflict-free)

// Workspace layout (float offsets)
#define HB0  0
#define HB1  131072
#define CB0  262144
#define CB1  393216
#define CNT  524288                 // 64 counters, stride 32 ints
#define GCNT (524288 + 2048)
#define AFB  528384                 // A-fragments: 204800 floats (hi+lo bf16 pairs)
#define XT   (528384 + 204800)      // xT: B*H*W*C = 4194304 floats
#define XT_N 4194304LL
#define WS_MIN   ((long long)XT)
#define WS_XT    ((long long)XT + XT_N)

__device__ __forceinline__ float sigm(float v) { return 1.f / (1.f + __expf(-v)); }
__device__ __forceinline__ float tanh_fast(float v) {
    float e = __expf(2.f * v);
    return 1.f - 2.f / (e + 1.f);
}

// Coherence-point (agent-scope) access: immune to per-XCD L2 staleness.
__device__ __forceinline__ float gload(const float* p) {
    return __hip_atomic_load((float*)p, __ATOMIC_RELAXED, __HIP_MEMORY_SCOPE_AGENT);
}
__device__ __forceinline__ void gstore(float* p, float v) {
    __hip_atomic_store(p, v, __ATOMIC_RELAXED, __HIP_MEMORY_SCOPE_AGENT);
}
__device__ __forceinline__ void wait_ge(int* p, int tgt) {
    while (__hip_atomic_load(p, __ATOMIC_RELAXED, __HIP_MEMORY_SCOPE_AGENT) < tgt)
        __builtin_amdgcn_s_sleep(1);
    __atomic_signal_fence(__ATOMIC_ACQUIRE);
}
__device__ __forceinline__ void bump(int* p) {
    __hip_atomic_fetch_add(p, 1, __ATOMIC_RELEASE, __HIP_MEMORY_SCOPE_AGENT);
}

__device__ __forceinline__ uint bf16hi(uint u) { return (u + 0x7FFFu + ((u >> 16) & 1u)) >> 16; }

// ---------------------------------------------------------------------------
// Prep: zero state+flags; build A-fragments (split-bf16, MFMA lane order);
// build xT[b][hr][w][c] for coalesced per-step x gather.
// ---------------------------------------------------------------------------
__global__ void lstm_prep(const float* __restrict__ x,
                          const float* __restrict__ w_is,
                          const float* __restrict__ w_ss,
                          float* __restrict__ ws, int use_xt, long long n_ws)
{
    const long long stride = (long long)gridDim.x * blockDim.x;
    const long long t0 = (long long)blockIdx.x * blockDim.x + threadIdx.x;

    // 1) zero state ping-pong + flags
    long long zt = (long long)AFB; if (zt > n_ws) zt = n_ws;
    for (long long i = t0; i < zt; i += stride) ws[i] = 0.f;

    // 2) A-fragments
    if (n_ws >= WS_MIN) {
        ushort* af = (ushort*)(ws + AFB);
        for (long long e = t0; e < 204800; e += stride) {
            int idx   = (int)e;
            int chunk = idx >> 9;           // (g*NRT+rt)*NKT + kt
            int lane  = (idx >> 3) & 63;
            int jj    = idx & 7;
            int g  = chunk / (NRT * NKT);
            int rm = chunk % (NRT * NKT);
            int rt = rm / NKT, kt = rm % NKT;
            int m = lane & 15, quad = lane >> 4;
            int r = rt * 16 + m;
            int q = r >> 5, hl = r & 31;
            int o = q * HD_ + g * GH + hl;
            int k = kt * 32 + quad * 8 + jj;
            float v;
            if (k < C_)            v = w_is[o * C_ + k];
            else if (k < C_ + HD_) v = w_ss[(o * HD_ + (k - C_)) * 2 + 1];
            else                   v = w_ss[(o * HD_ + (k - C_ - HD_)) * 2 + 0];
            uint uh = bf16hi(__float_as_uint(v));
            float rl = v - __uint_as_float(uh << 16);
            uint ul = bf16hi(__float_as_uint(rl));
            int base = chunk * 1024 + lane * 16 + jj;   // ushort units
            af[base]     = (ushort)uh;
            af[base + 8] = (ushort)ul;
        }
    }

    // 3) xT transpose: exactly B*H*W*C elements
    if (use_xt) {
        float* xt = ws + XT;
        for (long long e = t0; e < XT_N; e += stride) {
            int c  = (int)(e & 63);
            int w  = (int)((e >> 6) & 63);
            int hr = (int)((e >> 12) & 63);
            int b  = (int)(e >> 18);
            xt[e] = x[(((size_t)b * C_ + c) * H_ + hr) * W_ + w];
        }
    }
}

// ---------------------------------------------------------------------------
// Persistent kernel: 127 diagonal steps, cluster-local dataflow sync,
// GEMM via split-bf16 MFMA 16x16x32 with register-resident A-fragments.
// ---------------------------------------------------------------------------
__global__ void __launch_bounds__(NT) lstm_persist(
    const float* __restrict__ x,
    const float* __restrict__ ws_c,
    const float* __restrict__ b_is,
    const float* __restrict__ b_ss,
    float* __restrict__ out,
    float* __restrict__ ws,
    int use_xt)
{
    __shared__ float Ss[192 * SSTR];    // rows 0..63: x [k][col+1]; 64..191: h [i][col'] (17 wide); reused as gate panel [160][GPS]
    __shared__ uint  Bf[NKT * 576];     // B-fragments: per kt, 64 lanes x (16B hi + 16B lo), swizzled
    __shared__ float Cs[17 * GH];       // c panel [colp][hl]
    __shared__ float bias_s[ROWS];

    const int tid = threadIdx.x;
    const int cgp = blockIdx.x >> 2;
    const int g   = blockIdx.x & 3;
    const int n0  = cgp * TC;
    const int inb  = (n0 & 63) != 0;
    const int hasr = ((n0 + TC) & 63) != 0;

    int* cntp  = (int*)(ws + CNT);
    int* gcntp = (int*)(ws + GCNT);
    const float* xt = ws_c + XT;
    const uint4* afq = (const uint4*)(ws_c + AFB);

    if (tid < ROWS) {
        int q = tid >> 5, hl = tid & 31;
        int o = q * HD_ + g * GH + hl;
        bias_s[tid] = b_is[o] + b_ss[o];
    }

    const int lane = tid & 63;
    const int wv   = tid >> 6;          // wave = row-tile rt in [0,10)
    const int quad = lane >> 4;
    const int colc = lane & 15;
    uint* bfp = &Bf[lane * 8 + ((lane >> 2) << 2)];

    // ---- hoist A-fragments into registers (weights are step-invariant) ----
    bf16x8 Ahr[NKT], Alr[NKT];
    {
        const uint4* ap0 = afq + (size_t)((g * NRT + wv) * NKT) * 128 + lane * 2;
        #pragma unroll
        for (int kt = 0; kt < NKT; ++kt) {
            uint4 ha = ap0[kt * 128];
            uint4 la = ap0[kt * 128 + 1];
            Ahr[kt] = *(bf16x8*)&ha;
            Alr[kt] = *(bf16x8*)&la;
        }
    }

    for (int j = 0; j < SW_; ++j) {
        const float* hc = ws + ((j & 1) ? HB1 : HB0);
        const float* cc = ws + ((j & 1) ? CB1 : CB0);
        float*       hn = ws + ((j & 1) ? HB0 : HB1);
        float*       cn = ws + ((j & 1) ? CB0 : CB1);

        // ---- prefetch x for this step (state-independent; overlaps the wait) ----
        float xr[2];
        #pragma unroll
        for (int t = 0; t < 2; ++t) {
            int idx = tid + t * NT;
            xr[t] = 0.f;
            if (idx < C_ * TC) {
                int c = idx & 63, col = idx >> 6;
                int n = n0 + col, b = n >> 6, hr = n & 63;
                int w = j - hr;
                if ((unsigned)w < (unsigned)W_)
                    xr[t] = use_xt ? xt[(((size_t)b * H_ + hr) * W_ + w) * C_ + c]
                                   : x [(((size_t)b * C_ + c) * H_ + hr) * W_ + w];
            }
        }

        // ---- RAW wait: own cluster + left neighbor finished step j-1 ----
        if (j > 0 && tid == 0) {
            wait_ge(cntp + cgp * 32, 4 * j);
            if (inb) wait_ge(cntp + (cgp - 1) * 32, 4 * j);
        }
        __syncthreads();

        // ---- write prefetched x, gather h (17 cols) + c panel ----
        #pragma unroll
        for (int t = 0; t < 2; ++t) {
            int idx = tid + t * NT;
            if (idx < C_ * TC) {
                int c = idx & 63, col = idx >> 6;
                Ss[c * SSTR + col + 1] = xr[t];
            }
        }
        for (int idx = tid; idx < HD_ * 17; idx += NT) {
            int i = idx & 127, colp = idx >> 7;          // colp in [0,17)
            int n = n0 - 1 + colp;
            float v = (colp > 0 || inb) ? gload(hc + (size_t)n * HD_ + i) : 0.f;
            Ss[(64 + i) * SSTR + colp] = v;
        }
        if (tid < 17 * GH) {
            int colp = tid >> 5, hl = tid & 31;
            int n = n0 - 1 + colp;
            float v = (colp > 0 || inb) ? gload(cc + (size_t)n * HD_ + g * GH + hl) : 0.f;
            Cs[colp * GH + hl] = v;
        }
        __syncthreads();
        if (tid == 0) bump(gcntp + cgp * 32);   // all step-(j-1)-state reads done

        // ---- convert S panel to split-bf16 B-fragments ----
        // thread -> (kt = wv, lane): B[n=lane&15][k=kt*32+quad*8+jj]
        {
            int kb = wv * 32 + quad * 8;   // wv == kt (10 waves == 10 k-tiles)
            uint hv[4], lv[4];
            #pragma unroll
            for (int p = 0; p < 4; ++p) {
                int k0 = kb + 2 * p;
                // k<192: own col (col+1 slot); k>=192: shifted -> left slot (col)
                float v0 = (k0 < 192) ? Ss[k0 * SSTR + colc + 1] : Ss[(k0 - 128) * SSTR + colc];
                int k1 = k0 + 1;
                float v1 = (k1 < 192) ? Ss[k1 * SSTR + colc + 1] : Ss[(k1 - 128) * SSTR + colc];
                uint h0 = bf16hi(__float_as_uint(v0));
                uint h1 = bf16hi(__float_as_uint(v1));
                float r0 = v0 - __uint_as_float(h0 << 16);
                float r1 = v1 - __uint_as_float(h1 << 16);
                uint l0 = bf16hi(__float_as_uint(r0));
                uint l1 = bf16hi(__float_as_uint(r1));
                hv[p] = h0 | (h1 << 16);
                lv[p] = l0 | (l1 << 16);
            }
            uint* bp = bfp + wv * 576;
            *(uint4*)bp       = make_uint4(hv[0], hv[1], hv[2], hv[3]);
            *(uint4*)(bp + 4) = make_uint4(lv[0], lv[1], lv[2], lv[3]);
        }
        __syncthreads();

        // ---- GEMM: wave wv computes rows [wv*16, wv*16+16) x 16 cols, K=320 ----
        // 4-term split (hi*hi + hi*lo + lo*hi + lo*lo) for precision margin
        f32x4 acc = {0.f, 0.f, 0.f, 0.f};
        #pragma unroll
        for (int kt = 0; kt < NKT; ++kt) {
            const uint* bp = bfp + kt * 576;
            uint4 hb = *(const uint4*)bp;
            uint4 lb = *(const uint4*)(bp + 4);
            bf16x8 Bh = *(bf16x8*)&hb, Bl = *(bf16x8*)&lb;
            acc = __builtin_amdgcn_mfma_f32_16x16x32_bf16(Ahr[kt], Bh, acc, 0, 0, 0);
            acc = __builtin_amdgcn_mfma_f32_16x16x32_bf16(Ahr[kt], Bl, acc, 0, 0, 0);
            acc = __builtin_amdgcn_mfma_f32_16x16x32_bf16(Alr[kt], Bh, acc, 0, 0, 0);
            acc = __builtin_amdgcn_mfma_f32_16x16x32_bf16(Alr[kt], Bl, acc, 0, 0, 0);
        }

        // ---- write gates to LDS panel (C/D layout: row = quad*4+reg, col = lane&15) ----
        #pragma unroll
        for (int r = 0; r < 4; ++r)
            Ss[(wv * 16 + quad * 4 + r) * GPS + colc] = acc[r];

        // ---- WAR guard: right neighbor gathered step j-1 before we overwrite parity ----
        if (j > 0 && hasr && tid == 0) wait_ge(gcntp + (cgp + 1) * 32, 4 * j);
        __syncthreads();

        // ---- nonlinearity + state update; out-store deferred past the bump ----
        float hv_keep = 0.f;
        size_t out_idx = 0;
        int do_out = 0;
        if (tid < GH * TC) {
            int hl = tid & 31, col = tid >> 5;
            int n = n0 + col, b = n >> 6, hr = n & 63;
            int hd = g * GH + hl;
            float go  = Ss[(0 * GH + hl) * GPS + col] + bias_s[0 * GH + hl];
            float gfl = Ss[(1 * GH + hl) * GPS + col] + bias_s[1 * GH + hl];
            float gfu = Ss[(2 * GH + hl) * GPS + col] + bias_s[2 * GH + hl];
            float gi  = Ss[(3 * GH + hl) * GPS + col] + bias_s[3 * GH + hl];
            float gg  = Ss[(4 * GH + hl) * GPS + col] + bias_s[4 * GH + hl];
            float so = sigm(go), sfl = sigm(gfl), sfu = sigm(gfu), si = sigm(gi);
            float tg = tanh_fast(gg);
            float cp = Cs[(col + 1) * GH + hl];
            float cs = hr ? Cs[col * GH + hl] : 0.f;
            float cv = sfl * cp + sfu * cs + si * tg;
            float hv = so * tanh_fast(cv);
            size_t sidx = (size_t)n * HD_ + hd;
            gstore(cn + sidx, cv);
            gstore(hn + sidx, hv);
            int w = j - hr;
            if ((unsigned)w < (unsigned)W_) {
                do_out = 1;
                hv_keep = hv;
                out_idx = (((size_t)b * HD_ + hd) * H_ + hr) * W_ + w;
            }
        }
        __syncthreads();                         // per-wave vmcnt drain -> state visible
        if (tid == 0) bump(cntp + cgp * 32);     // step j finished
        if (do_out) out[out_idx] = hv_keep;      // scattered store drains off critical path
    }
}

// ---------------------------------------------------------------------------
extern "C" void kernel_launch(void* const* d_in, const int* in_sizes, int n_in,
                              void* d_out, int out_size, void* d_ws, size_t ws_size,
                              hipStream_t stream)
{
    const float* x    = (const float*)d_in[0];
    const float* w_is = (const float*)d_in[1];
    const float* b_is = (const float*)d_in[2];
    const float* w_ss = (const float*)d_in[3];
    const float* b_ss = (const float*)d_in[4];
    float* out = (float*)d_out;
    float* ws  = (float*)d_ws;

    const long long n_ws = (long long)(ws_size / 4);
    const int use_xt = (n_ws >= WS_XT) ? 1 : 0;

    hipLaunchKernelGGL(lstm_prep, dim3(2048), dim3(256), 0, stream,
                       x, w_is, w_ss, ws, use_xt, n_ws);

    hipLaunchKernelGGL(lstm_persist, dim3(NG * NCG), dim3(NT), 0, stream,
                       x, ws, b_is, b_ss, out, ws, use_xt);
}

// Round 7
// 1944.216 us; speedup vs baseline: 1.0643x; 1.0643x over previous
//
#include <hip/hip_runtime.h>

typedef __attribute__((ext_vector_type(8))) short bf16x8;
typedef __attribute__((ext_vector_type(4))) float f32x4;

// Problem constants
#define B_   16
#define C_   64
#define H_   64
#define W_   64
#define HD_  128
#define K_   320      // C + 2*HD
#define SW_  127      // H+W-1

// Decomposition: 4 hd-groups (32 hd each) x 64 col-clusters (16 cols each) = 256 blocks
#define NG    4
#define GH    32      // hd per group
#define NCG   64      // clusters
#define TC    16      // cols per cluster
#define NT    640     // threads per block (10 waves)
#define ROWS  160     // gate rows per block (5 gates x 32 hd)
#define NKT   10      // K/32 k-tiles
#define NRT   10      // ROWS/16 row-tiles (== waves)
#define SSTR  19      // Ss row stride
#define GPS   17      // gate-panel stride

// Workspace layout (float offsets)
#define HB0  0
#define HB1  131072
#define CBX  262144                 // c boundary exchange: 2 parities x 64 clusters x 4 g x 32 = 16384 floats
#define CNT  524288                 // 64 counters, stride 32 ints
#define GCNT (524288 + 2048)
#define AFB  528384                 // A-fragments: 204800 floats (hi+lo bf16 pairs)
#define XT   (528384 + 204800)      // xT: B*H*W*C = 4194304 floats
#define XT_N 4194304LL
#define WS_MIN   ((long long)XT)
#define WS_XT    ((long long)XT + XT_N)

__device__ __forceinline__ float sigm(float v) { return 1.f / (1.f + __expf(-v)); }
__device__ __forceinline__ float tanh_fast(float v) {
    float e = __expf(2.f * v);
    return 1.f - 2.f / (e + 1.f);
}

// Flags: relaxed agent-scope atomics. Data: normal cached ops, made coherent by
// agent-scope release fence (producer, before bump) + acquire fence (consumer, after spin).
__device__ __forceinline__ int rload(int* p) {
    return __hip_atomic_load(p, __ATOMIC_RELAXED, __HIP_MEMORY_SCOPE_AGENT);
}
__device__ __forceinline__ void rbump(int* p) {
    __hip_atomic_fetch_add(p, 1, __ATOMIC_RELAXED, __HIP_MEMORY_SCOPE_AGENT);
}
__device__ __forceinline__ void wait_ge(int* p, int tgt) {
    while (rload(p) < tgt) __builtin_amdgcn_s_sleep(1);
    __atomic_signal_fence(__ATOMIC_ACQUIRE);
}
__device__ __forceinline__ void fence_acq() { __builtin_amdgcn_fence(__ATOMIC_ACQUIRE, "agent"); }
__device__ __forceinline__ void fence_rel() { __builtin_amdgcn_fence(__ATOMIC_RELEASE, "agent"); }

__device__ __forceinline__ uint bf16hi(uint u) { return (u + 0x7FFFu + ((u >> 16) & 1u)) >> 16; }

// ---------------------------------------------------------------------------
// Prep: zero state+flags; build A-fragments (split-bf16, MFMA lane order);
// build xT[b][hr][w][c] for coalesced per-step x gather.
// ---------------------------------------------------------------------------
__global__ void lstm_prep(const float* __restrict__ x,
                          const float* __restrict__ w_is,
                          const float* __restrict__ w_ss,
                          float* __restrict__ ws, int use_xt, long long n_ws)
{
    const long long stride = (long long)gridDim.x * blockDim.x;
    const long long t0 = (long long)blockIdx.x * blockDim.x + threadIdx.x;

    // 1) zero h ping-pong + cbx + flags
    long long zt = (long long)AFB; if (zt > n_ws) zt = n_ws;
    for (long long i = t0; i < zt; i += stride) ws[i] = 0.f;

    // 2) A-fragments
    if (n_ws >= WS_MIN) {
        ushort* af = (ushort*)(ws + AFB);
        for (long long e = t0; e < 204800; e += stride) {
            int idx   = (int)e;
            int chunk = idx >> 9;           // (g*NRT+rt)*NKT + kt
            int lane  = (idx >> 3) & 63;
            int jj    = idx & 7;
            int g  = chunk / (NRT * NKT);
            int rm = chunk % (NRT * NKT);
            int rt = rm / NKT, kt = rm % NKT;
            int m = lane & 15, quad = lane >> 4;
            int r = rt * 16 + m;
            int q = r >> 5, hl = r & 31;
            int o = q * HD_ + g * GH + hl;
            int k = kt * 32 + quad * 8 + jj;
            float v;
            if (k < C_)            v = w_is[o * C_ + k];
            else if (k < C_ + HD_) v = w_ss[(o * HD_ + (k - C_)) * 2 + 1];
            else                   v = w_ss[(o * HD_ + (k - C_ - HD_)) * 2 + 0];
            uint uh = bf16hi(__float_as_uint(v));
            float rl = v - __uint_as_float(uh << 16);
            uint ul = bf16hi(__float_as_uint(rl));
            int base = chunk * 1024 + lane * 16 + jj;   // ushort units
            af[base]     = (ushort)uh;
            af[base + 8] = (ushort)ul;
        }
    }

    // 3) xT transpose: exactly B*H*W*C elements
    if (use_xt) {
        float* xt = ws + XT;
        for (long long e = t0; e < XT_N; e += stride) {
            int c  = (int)(e & 63);
            int w  = (int)((e >> 6) & 63);
            int hr = (int)((e >> 12) & 63);
            int b  = (int)(e >> 18);
            xt[e] = x[(((size_t)b * C_ + c) * H_ + hr) * W_ + w];
        }
    }
}

// ---------------------------------------------------------------------------
// Persistent kernel: 127 diagonal steps, cluster-local dataflow sync.
// Data via normal cached ops + per-step agent release/acquire fences.
// c-state lives in LDS (only a 32-float boundary column crosses blocks).
// ---------------------------------------------------------------------------
__global__ void __launch_bounds__(NT) lstm_persist(
    const float* __restrict__ x,
    const float* __restrict__ ws_c,
    const float* __restrict__ b_is,
    const float* __restrict__ b_ss,
    float* __restrict__ out,
    float* __restrict__ ws,
    int use_xt)
{
    __shared__ float Ss[192 * SSTR];    // rows 0..63: x [k][col+1]; 64..191: h [i][colp]; aliased as gate panel [160][GPS]
    __shared__ uint  Bf[NKT * 576];     // B-fragments: per kt, 64 lanes x (16B hi + 16B lo), swizzled
    __shared__ float Cs[17 * GH];       // persistent c panel [colp][hl], colp 0 = left boundary
    __shared__ float bias_s[ROWS];

    const int tid = threadIdx.x;
    const int cgp = blockIdx.x >> 2;
    const int g   = blockIdx.x & 3;
    const int n0  = cgp * TC;
    const int inb  = (n0 & 63) != 0;
    const int hasr = ((n0 + TC) & 63) != 0;

    int* cntp  = (int*)(ws + CNT);
    int* gcntp = (int*)(ws + GCNT);
    float* cbx = ws + CBX;
    const float* xt = ws_c + XT;
    const uint4* afq = (const uint4*)(ws_c + AFB);

    if (tid < ROWS) {
        int q = tid >> 5, hl = tid & 31;
        int o = q * HD_ + g * GH + hl;
        bias_s[tid] = b_is[o] + b_ss[o];
    }
    if (tid < 17 * GH) Cs[tid] = 0.f;   // c(0) = 0

    const int lane = tid & 63;
    const int wv   = tid >> 6;          // wave = row-tile rt in [0,10)
    const int quad = lane >> 4;
    const int colc = lane & 15;
    uint* bfp = &Bf[lane * 8 + ((lane >> 2) << 2)];
    const uint4* ap0 = afq + (size_t)((g * NRT + wv) * NKT) * 128 + lane * 2;

    for (int j = 0; j < SW_; ++j) {
        const float* hc = ws + ((j & 1) ? HB1 : HB0);
        float*       hn = ws + ((j & 1) ? HB0 : HB1);

        // ---- prefetch x for this step (state-independent; overlaps the wait) ----
        float xr[2];
        #pragma unroll
        for (int t = 0; t < 2; ++t) {
            int idx = tid + t * NT;
            xr[t] = 0.f;
            if (idx < C_ * TC) {
                int c = idx & 63, col = idx >> 6;
                int n = n0 + col, b = n >> 6, hr = n & 63;
                int w = j - hr;
                if ((unsigned)w < (unsigned)W_)
                    xr[t] = use_xt ? xt[(((size_t)b * H_ + hr) * W_ + w) * C_ + c]
                                   : x [(((size_t)b * C_ + c) * H_ + hr) * W_ + w];
            }
        }

        // ---- RAW wait + acquire fence: step j-1 data (h, cbx) becomes safe to read ----
        if (j > 0 && tid == 0) {
            wait_ge(cntp + cgp * 32, 4 * j);
            if (inb) wait_ge(cntp + (cgp - 1) * 32, 4 * j);
            fence_acq();                 // invalidate stale L1/L2 copies of h/cbx
        }
        __syncthreads();

        // ---- gather: x (prefetched), h (17 cols, normal cached loads), c boundary ----
        #pragma unroll
        for (int t = 0; t < 2; ++t) {
            int idx = tid + t * NT;
            if (idx < C_ * TC) {
                int c = idx & 63, col = idx >> 6;
                Ss[c * SSTR + col + 1] = xr[t];
            }
        }
        for (int idx = tid; idx < HD_ * 17; idx += NT) {
            int i = idx & 127, colp = idx >> 7;          // colp in [0,17)
            int n = n0 - 1 + colp;
            float v = (colp > 0 || inb) ? hc[(size_t)n * HD_ + i] : 0.f;
            Ss[(64 + i) * SSTR + colp] = v;
        }
        if (tid < GH) {
            float v = 0.f;
            if (inb && j > 0)
                v = cbx[(((size_t)((j - 1) & 1) * NCG + (cgp - 1)) * NG + g) * GH + tid];
            Cs[tid] = v;                                 // colp = 0 boundary column
        }
        __syncthreads();
        if (tid == 0) rbump(gcntp + cgp * 32);           // all step-(j-1)-state reads done (WAR token)

        // ---- convert S panel to split-bf16 B-fragments ----
        {
            int kb = wv * 32 + quad * 8;   // wv == kt (10 waves == 10 k-tiles)
            uint hv[4], lv[4];
            #pragma unroll
            for (int p = 0; p < 4; ++p) {
                int k0 = kb + 2 * p;
                float v0 = (k0 < 192) ? Ss[k0 * SSTR + colc + 1] : Ss[(k0 - 128) * SSTR + colc];
                int k1 = k0 + 1;
                float v1 = (k1 < 192) ? Ss[k1 * SSTR + colc + 1] : Ss[(k1 - 128) * SSTR + colc];
                uint h0 = bf16hi(__float_as_uint(v0));
                uint h1 = bf16hi(__float_as_uint(v1));
                float r0 = v0 - __uint_as_float(h0 << 16);
                float r1 = v1 - __uint_as_float(h1 << 16);
                uint l0 = bf16hi(__float_as_uint(r0));
                uint l1 = bf16hi(__float_as_uint(r1));
                hv[p] = h0 | (h1 << 16);
                lv[p] = l0 | (l1 << 16);
            }
            uint* bp = bfp + wv * 576;
            *(uint4*)bp       = make_uint4(hv[0], hv[1], hv[2], hv[3]);
            *(uint4*)(bp + 4) = make_uint4(lv[0], lv[1], lv[2], lv[3]);
        }
        __syncthreads();

        // ---- GEMM: wave wv computes rows [wv*16, wv*16+16) x 16 cols, K=320, 4-term split ----
        f32x4 acc = {0.f, 0.f, 0.f, 0.f};
        #pragma unroll
        for (int kt = 0; kt < NKT; ++kt) {
            uint4 ha = ap0[kt * 128];
            uint4 la = ap0[kt * 128 + 1];
            const uint* bp = bfp + kt * 576;
            uint4 hb = *(const uint4*)bp;
            uint4 lb = *(const uint4*)(bp + 4);
            bf16x8 Ah = *(bf16x8*)&ha, Al = *(bf16x8*)&la;
            bf16x8 Bh = *(bf16x8*)&hb, Bl = *(bf16x8*)&lb;
            acc = __builtin_amdgcn_mfma_f32_16x16x32_bf16(Ah, Bh, acc, 0, 0, 0);
            acc = __builtin_amdgcn_mfma_f32_16x16x32_bf16(Ah, Bl, acc, 0, 0, 0);
            acc = __builtin_amdgcn_mfma_f32_16x16x32_bf16(Al, Bh, acc, 0, 0, 0);
            acc = __builtin_amdgcn_mfma_f32_16x16x32_bf16(Al, Bl, acc, 0, 0, 0);
        }

        // ---- write gates to LDS panel (C/D layout: row = quad*4+reg, col = lane&15) ----
        #pragma unroll
        for (int r = 0; r < 4; ++r)
            Ss[(wv * 16 + quad * 4 + r) * GPS + colc] = acc[r];

        // ---- WAR guard: right neighbor gathered step j-1 before we overwrite h parity / cbx ----
        if (j > 0 && hasr && tid == 0) wait_ge(gcntp + (cgp + 1) * 32, 4 * j);
        __syncthreads();

        // ---- nonlinearity + state update (c in LDS), h store, out deferred ----
        float hv_keep = 0.f, cv_keep = 0.f;
        size_t out_idx = 0;
        int do_out = 0, active = (tid < GH * TC);
        int hl = tid & 31, col = tid >> 5;
        if (active) {
            int n = n0 + col, b = n >> 6, hr = n & 63;
            int hd = g * GH + hl;
            float go  = Ss[(0 * GH + hl) * GPS + col] + bias_s[0 * GH + hl];
            float gfl = Ss[(1 * GH + hl) * GPS + col] + bias_s[1 * GH + hl];
            float gfu = Ss[(2 * GH + hl) * GPS + col] + bias_s[2 * GH + hl];
            float gi  = Ss[(3 * GH + hl) * GPS + col] + bias_s[3 * GH + hl];
            float gg  = Ss[(4 * GH + hl) * GPS + col] + bias_s[4 * GH + hl];
            float so = sigm(go), sfl = sigm(gfl), sfu = sigm(gfu), si = sigm(gi);
            float tg = tanh_fast(gg);
            float cp = Cs[(col + 1) * GH + hl];
            float cs = Cs[col * GH + hl];                 // col 0 -> boundary (0 if !inb)
            float cv = sfl * cp + sfu * cs + si * tg;
            float hv = so * tanh_fast(cv);
            cv_keep = cv; hv_keep = hv;
            hn[(size_t)n * HD_ + g * GH + hl] = hv;       // normal cached store
            int w = j - hr;
            if ((unsigned)w < (unsigned)W_) {
                do_out = 1;
                out_idx = (((size_t)b * HD_ + hd) * H_ + hr) * W_ + w;
            }
        }
        __syncthreads();                                  // all Cs reads done before overwrite
        if (active) {
            Cs[(col + 1) * GH + hl] = cv_keep;
            if (col == TC - 1)                            // export boundary col for right neighbor
                cbx[(((size_t)(j & 1) * NCG + cgp) * NG + g) * GH + hl] = cv_keep;
        }
        __syncthreads();                                  // h/cbx stores complete (per-wave vmcnt drain)
        if (tid == 0) {
            fence_rel();                                  // write back dirty L2 -> coherence point
            rbump(cntp + cgp * 32);                       // step j finished
        }
        if (do_out) out[out_idx] = hv_keep;               // off critical path
    }
}

// ---------------------------------------------------------------------------
extern "C" void kernel_launch(void* const* d_in, const int* in_sizes, int n_in,
                              void* d_out, int out_size, void* d_ws, size_t ws_size,
                              hipStream_t stream)
{
    const float* x    = (const float*)d_in[0];
    const float* w_is = (const float*)d_in[1];
    const float* b_is = (const float*)d_in[2];
    const float* w_ss = (const float*)d_in[3];
    const float* b_ss = (const float*)d_in[4];
    float* out = (float*)d_out;
    float* ws  = (float*)d_ws;

    const long long n_ws = (long long)(ws_size / 4);
    const int use_xt = (n_ws >= WS_XT) ? 1 : 0;

    hipLaunchKernelGGL(lstm_prep, dim3(2048), dim3(256), 0, stream,
                       x, w_is, w_ss, ws, use_xt, n_ws);

    hipLaunchKernelGGL(lstm_persist, dim3(NG * NCG), dim3(NT), 0, stream,
                       x, ws, b_is, b_ss, out, ws, use_xt);
}

// Round 8
// 753.684 us; speedup vs baseline: 2.7455x; 2.5796x over previous
//
#include <hip/hip_runtime.h>

typedef __attribute__((ext_vector_type(8))) short bf16x8;
typedef __attribute__((ext_vector_type(4))) float f32x4;

// Problem constants
#define B_   16
#define C_   64
#define H_   64
#define W_   64
#define HD_  128
#define K_   320      // C + 2*HD
#define SW_  127      // H+W-1

// Decomposition: 4 hd-groups (32 hd each) x 64 col-clusters (16 cols each) = 256 blocks
#define NG    4
#define GH    32      // hd per group
#define NCG   64      // clusters
#define TC    16      // cols per cluster
#define NT    640     // threads per block (10 waves)
#define ROWS  160     // gate rows per block (5 gates x 32 hd)
#define NKT   10      // K/32 k-tiles
#define NRT   10      // ROWS/16 row-tiles (== waves)
#define SSTR  19      // Ss row stride
#define GPS   17      // gate-panel stride

// Workspace layout (float offsets)
#define HB0  0
#define HB1  131072
#define CBX  262144                 // c boundary exchange: 2 parities x 64 clusters x 4 g x 32
#define CNT  524288                 // 64 counters, stride 32 ints
#define GCNT (524288 + 2048)
#define AFB  528384                 // A-fragments: 204800 floats (hi+lo bf16 pairs)
#define XT   (528384 + 204800)      // xT: B*H*W*C = 4194304 floats
#define XT_N 4194304LL
#define WS_MIN   ((long long)XT)
#define WS_XT    ((long long)XT + XT_N)

__device__ __forceinline__ float sigm(float v) { return 1.f / (1.f + __expf(-v)); }
__device__ __forceinline__ float tanh_fast(float v) {
    float e = __expf(2.f * v);
    return 1.f - 2.f / (e + 1.f);
}

// Flags: relaxed agent-scope atomics (coherence point).
__device__ __forceinline__ int rload(int* p) {
    return __hip_atomic_load(p, __ATOMIC_RELAXED, __HIP_MEMORY_SCOPE_AGENT);
}
__device__ __forceinline__ void rbump(int* p) {
    __hip_atomic_fetch_add(p, 1, __ATOMIC_RELAXED, __HIP_MEMORY_SCOPE_AGENT);
}
__device__ __forceinline__ void wait_ge(int* p, int tgt) {
    while (rload(p) < tgt) { }       // busy poll: lowest discovery latency
    __atomic_signal_fence(__ATOMIC_ACQUIRE);
}

// Coherence-point (sc0 sc1) data ops: bypass L1/L2, no fences needed, and the
// rest of L2 (A-frags, xT) is never invalidated.
__device__ __forceinline__ f32x4 ld4_sc(const float* p) {
    f32x4 v;
    asm volatile("global_load_dwordx4 %0, %1, off sc0 sc1\n\ts_waitcnt vmcnt(0)"
                 : "=v"(v) : "v"(p) : "memory");
    return v;
}
__device__ __forceinline__ float ld1_sc(const float* p) {
    float v;
    asm volatile("global_load_dword %0, %1, off sc0 sc1\n\ts_waitcnt vmcnt(0)"
                 : "=v"(v) : "v"(p) : "memory");
    return v;
}
__device__ __forceinline__ void st1_sc(float* p, float v) {
    asm volatile("global_store_dword %0, %1, off sc0 sc1\n\ts_waitcnt vmcnt(0)"
                 :: "v"(p), "v"(v) : "memory");
}

__device__ __forceinline__ uint bf16hi(uint u) { return (u + 0x7FFFu + ((u >> 16) & 1u)) >> 16; }

// ---------------------------------------------------------------------------
// Prep: zero state+flags; build A-fragments (split-bf16, MFMA lane order);
// build xT[b][hr][w][c] for coalesced per-step x gather.
// ---------------------------------------------------------------------------
__global__ void lstm_prep(const float* __restrict__ x,
                          const float* __restrict__ w_is,
                          const float* __restrict__ w_ss,
                          float* __restrict__ ws, int use_xt, long long n_ws)
{
    const long long stride = (long long)gridDim.x * blockDim.x;
    const long long t0 = (long long)blockIdx.x * blockDim.x + threadIdx.x;

    long long zt = (long long)AFB; if (zt > n_ws) zt = n_ws;
    for (long long i = t0; i < zt; i += stride) ws[i] = 0.f;

    if (n_ws >= WS_MIN) {
        ushort* af = (ushort*)(ws + AFB);
        for (long long e = t0; e < 204800; e += stride) {
            int idx   = (int)e;
            int chunk = idx >> 9;           // (g*NRT+rt)*NKT + kt
            int lane  = (idx >> 3) & 63;
            int jj    = idx & 7;
            int g  = chunk / (NRT * NKT);
            int rm = chunk % (NRT * NKT);
            int rt = rm / NKT, kt = rm % NKT;
            int m = lane & 15, quad = lane >> 4;
            int r = rt * 16 + m;
            int q = r >> 5, hl = r & 31;
            int o = q * HD_ + g * GH + hl;
            int k = kt * 32 + quad * 8 + jj;
            float v;
            if (k < C_)            v = w_is[o * C_ + k];
            else if (k < C_ + HD_) v = w_ss[(o * HD_ + (k - C_)) * 2 + 1];
            else                   v = w_ss[(o * HD_ + (k - C_ - HD_)) * 2 + 0];
            uint uh = bf16hi(__float_as_uint(v));
            float rl = v - __uint_as_float(uh << 16);
            uint ul = bf16hi(__float_as_uint(rl));
            int base = chunk * 1024 + lane * 16 + jj;   // ushort units
            af[base]     = (ushort)uh;
            af[base + 8] = (ushort)ul;
        }
    }

    if (use_xt) {
        float* xt = ws + XT;
        for (long long e = t0; e < XT_N; e += stride) {
            int c  = (int)(e & 63);
            int w  = (int)((e >> 6) & 63);
            int hr = (int)((e >> 12) & 63);
            int b  = (int)(e >> 18);
            xt[e] = x[(((size_t)b * C_ + c) * H_ + hr) * W_ + w];
        }
    }
}

// ---------------------------------------------------------------------------
// Persistent kernel: 127 diagonal steps, cluster-local dataflow sync.
// h/cbx exchanged via sc0sc1 coherence-point ops (no fences; L2 stays warm
// for A-fragments and xT). c-state resident in LDS.
// ---------------------------------------------------------------------------
__global__ void __launch_bounds__(NT) lstm_persist(
    const float* __restrict__ x,
    const float* __restrict__ ws_c,
    const float* __restrict__ b_is,
    const float* __restrict__ b_ss,
    float* __restrict__ out,
    float* __restrict__ ws,
    int use_xt)
{
    __shared__ float Ss[192 * SSTR];    // rows 0..63: x [k][col+1]; 64..191: h [i][colp]; aliased gate panel [160][GPS]
    __shared__ uint  Bf[NKT * 576];     // B-fragments: per kt, 64 lanes x (16B hi + 16B lo), swizzled
    __shared__ float Cs[17 * GH];       // persistent c panel [colp][hl], colp 0 = left boundary
    __shared__ float bias_s[ROWS];

    const int tid = threadIdx.x;
    const int cgp = blockIdx.x >> 2;
    const int g   = blockIdx.x & 3;
    const int n0  = cgp * TC;
    const int inb  = (n0 & 63) != 0;
    const int hasr = ((n0 + TC) & 63) != 0;

    int* cntp  = (int*)(ws + CNT);
    int* gcntp = (int*)(ws + GCNT);
    float* cbx = ws + CBX;
    const float* xt = ws_c + XT;
    const uint4* afq = (const uint4*)(ws_c + AFB);

    if (tid < ROWS) {
        int q = tid >> 5, hl = tid & 31;
        int o = q * HD_ + g * GH + hl;
        bias_s[tid] = b_is[o] + b_ss[o];
    }
    if (tid < 17 * GH) Cs[tid] = 0.f;   // c(0) = 0

    const int lane = tid & 63;
    const int wv   = tid >> 6;          // wave = row-tile rt in [0,10)
    const int quad = lane >> 4;
    const int colc = lane & 15;
    uint* bfp = &Bf[lane * 8 + ((lane >> 2) << 2)];
    const uint4* ap0 = afq + (size_t)((g * NRT + wv) * NKT) * 128 + lane * 2;

    // ---- A-hi fragments pinned in registers (asm anchor = sole def, cannot sink) ----
    bf16x8 Ahr[NKT];
    #pragma unroll
    for (int kt = 0; kt < NKT; ++kt) {
        uint4 ha = ap0[kt * 128];
        Ahr[kt] = *(bf16x8*)&ha;
        asm volatile("" : "+v"(Ahr[kt]));
    }

    for (int j = 0; j < SW_; ++j) {
        const float* hc = ws + ((j & 1) ? HB1 : HB0);
        float*       hn = ws + ((j & 1) ? HB0 : HB1);

        // ---- prefetch x for this step (state-independent; overlaps the wait) ----
        float xr[2];
        #pragma unroll
        for (int t = 0; t < 2; ++t) {
            int idx = tid + t * NT;
            xr[t] = 0.f;
            if (idx < C_ * TC) {
                int c = idx & 63, col = idx >> 6;
                int n = n0 + col, b = n >> 6, hr = n & 63;
                int w = j - hr;
                if ((unsigned)w < (unsigned)W_)
                    xr[t] = use_xt ? xt[(((size_t)b * H_ + hr) * W_ + w) * C_ + c]
                                   : x [(((size_t)b * C_ + c) * H_ + hr) * W_ + w];
            }
        }

        // ---- RAW wait: own cluster + left neighbor finished step j-1 ----
        if (j > 0 && tid == 0) {
            wait_ge(cntp + cgp * 32, 4 * j);
            if (inb) wait_ge(cntp + (cgp - 1) * 32, 4 * j);
        }
        __syncthreads();

        // ---- x write + h gather (sc1 float4, one per thread) + c boundary ----
        #pragma unroll
        for (int t = 0; t < 2; ++t) {
            int idx = tid + t * NT;
            if (idx < C_ * TC) {
                int c = idx & 63, col = idx >> 6;
                Ss[c * SSTR + col + 1] = xr[t];
            }
        }
        if (tid < 544) {                                 // 17 cols x 32 float4
            int colp = tid >> 5, i4 = tid & 31;
            int n = n0 - 1 + colp;
            f32x4 v = {0.f, 0.f, 0.f, 0.f};
            if (colp > 0 || inb) v = ld4_sc(hc + (size_t)n * HD_ + i4 * 4);
            #pragma unroll
            for (int r = 0; r < 4; ++r)
                Ss[(64 + i4 * 4 + r) * SSTR + colp] = v[r];
        } else if (tid >= 576 && tid < 576 + GH) {       // c boundary column
            int hl = tid - 576;
            float v = 0.f;
            if (inb && j > 0)
                v = ld1_sc(cbx + (((size_t)((j - 1) & 1) * NCG + (cgp - 1)) * NG + g) * GH + hl);
            Cs[hl] = v;
        }
        __syncthreads();
        if (tid == 0) rbump(gcntp + cgp * 32);           // step-(j-1) state fully read (WAR token)

        // ---- convert S panel to split-bf16 B-fragments (kt = wv) ----
        {
            int kb = wv * 32 + quad * 8;
            uint hv[4], lv[4];
            #pragma unroll
            for (int p = 0; p < 4; ++p) {
                int k0 = kb + 2 * p;
                float v0 = (k0 < 192) ? Ss[k0 * SSTR + colc + 1] : Ss[(k0 - 128) * SSTR + colc];
                int k1 = k0 + 1;
                float v1 = (k1 < 192) ? Ss[k1 * SSTR + colc + 1] : Ss[(k1 - 128) * SSTR + colc];
                uint h0 = bf16hi(__float_as_uint(v0));
                uint h1 = bf16hi(__float_as_uint(v1));
                float r0 = v0 - __uint_as_float(h0 << 16);
                float r1 = v1 - __uint_as_float(h1 << 16);
                uint l0 = bf16hi(__float_as_uint(r0));
                uint l1 = bf16hi(__float_as_uint(r1));
                hv[p] = h0 | (h1 << 16);
                lv[p] = l0 | (l1 << 16);
            }
            uint* bp = bfp + wv * 576;
            *(uint4*)bp       = make_uint4(hv[0], hv[1], hv[2], hv[3]);
            *(uint4*)(bp + 4) = make_uint4(lv[0], lv[1], lv[2], lv[3]);
        }
        __syncthreads();

        // ---- GEMM: rows [wv*16, wv*16+16) x 16 cols, K=320; A-hi in regs, A-lo from L2 ----
        f32x4 acc = {0.f, 0.f, 0.f, 0.f};
        #pragma unroll
        for (int kt = 0; kt < NKT; ++kt) {
            uint4 la = ap0[kt * 128 + 1];
            bf16x8 Al = *(bf16x8*)&la;
            const uint* bp = bfp + kt * 576;
            uint4 hb = *(const uint4*)bp;
            uint4 lb = *(const uint4*)(bp + 4);
            bf16x8 Bh = *(bf16x8*)&hb, Bl = *(bf16x8*)&lb;
            acc = __builtin_amdgcn_mfma_f32_16x16x32_bf16(Ahr[kt], Bh, acc, 0, 0, 0);
            acc = __builtin_amdgcn_mfma_f32_16x16x32_bf16(Ahr[kt], Bl, acc, 0, 0, 0);
            acc = __builtin_amdgcn_mfma_f32_16x16x32_bf16(Al,      Bh, acc, 0, 0, 0);
            acc = __builtin_amdgcn_mfma_f32_16x16x32_bf16(Al,      Bl, acc, 0, 0, 0);
        }

        // ---- gates to LDS (C/D layout: row = quad*4+reg, col = lane&15) ----
        #pragma unroll
        for (int r = 0; r < 4; ++r)
            Ss[(wv * 16 + quad * 4 + r) * GPS + colc] = acc[r];

        // ---- WAR guard: right neighbor consumed step j-1 before we overwrite parity ----
        if (j > 0 && hasr && tid == 0) wait_ge(gcntp + (cgp + 1) * 32, 4 * j);
        __syncthreads();

        // ---- nonlinearity + state update; h via sc1 store; out deferred ----
        float hv_keep = 0.f, cv_keep = 0.f;
        size_t out_idx = 0;
        int do_out = 0, active = (tid < GH * TC);
        int hl = tid & 31, col = tid >> 5;
        if (active) {
            int n = n0 + col, b = n >> 6, hr = n & 63;
            int hd = g * GH + hl;
            float go  = Ss[(0 * GH + hl) * GPS + col] + bias_s[0 * GH + hl];
            float gfl = Ss[(1 * GH + hl) * GPS + col] + bias_s[1 * GH + hl];
            float gfu = Ss[(2 * GH + hl) * GPS + col] + bias_s[2 * GH + hl];
            float gi  = Ss[(3 * GH + hl) * GPS + col] + bias_s[3 * GH + hl];
            float gg  = Ss[(4 * GH + hl) * GPS + col] + bias_s[4 * GH + hl];
            float so = sigm(go), sfl = sigm(gfl), sfu = sigm(gfu), si = sigm(gi);
            float tg = tanh_fast(gg);
            float cp = Cs[(col + 1) * GH + hl];
            float cs = Cs[col * GH + hl];
            float cv = sfl * cp + sfu * cs + si * tg;
            float hv = so * tanh_fast(cv);
            cv_keep = cv; hv_keep = hv;
            st1_sc(hn + (size_t)n * HD_ + g * GH + hl, hv);
            int w = j - hr;
            if ((unsigned)w < (unsigned)W_) {
                do_out = 1;
                out_idx = (((size_t)b * HD_ + hd) * H_ + hr) * W_ + w;
            }
        }
        __syncthreads();                                  // Cs reads done before overwrite
        if (active) {
            Cs[(col + 1) * GH + hl] = cv_keep;
            if (col == TC - 1)
                st1_sc(cbx + (((size_t)(j & 1) * NCG + cgp) * NG + g) * GH + hl, cv_keep);
        }
        __syncthreads();                                  // all sc1 stores drained (asm-internal waitcnt)
        if (tid == 0) rbump(cntp + cgp * 32);             // step j finished
        if (do_out) out[out_idx] = hv_keep;               // plain cached, off critical path
    }
}

// ---------------------------------------------------------------------------
extern "C" void kernel_launch(void* const* d_in, const int* in_sizes, int n_in,
                              void* d_out, int out_size, void* d_ws, size_t ws_size,
                              hipStream_t stream)
{
    const float* x    = (const float*)d_in[0];
    const float* w_is = (const float*)d_in[1];
    const float* b_is = (const float*)d_in[2];
    const float* w_ss = (const float*)d_in[3];
    const float* b_ss = (const float*)d_in[4];
    float* out = (float*)d_out;
    float* ws  = (float*)d_ws;

    const long long n_ws = (long long)(ws_size / 4);
    const int use_xt = (n_ws >= WS_XT) ? 1 : 0;

    hipLaunchKernelGGL(lstm_prep, dim3(2048), dim3(256), 0, stream,
                       x, w_is, w_ss, ws, use_xt, n_ws);

    hipLaunchKernelGGL(lstm_persist, dim3(NG * NCG), dim3(NT), 0, stream,
                       x, ws, b_is, b_ss, out, ws, use_xt);
}